// Round 5
// baseline (185.928 us; speedup 1.0000x reference)
//
#include <hip/hip_runtime.h>
#include <math.h>

#define B 64
#define C 100
#define K 5
#define N (B*C*K)   // 32000
#define M 4096      // L1 bucket count (log-spaced over u)
#define GRID 80     // 80 blocks x 256 thr = 320 waves; all co-resident on 256 CUs
#define BLK 256

#define ALPHA 0.7f
#define L1L2_SCALE 0.00025f

#define SCAN_T 256
#define PER_T (M / SCAN_T)   // 16

// acc layout (floats):
// 0: KL acc  1: CE acc  2: tt  3: ss  4: ts  5: sum G^2  6: sum H^2  7: L1 sum
// 12: grid barrier counter (int)

__device__ __forceinline__ float waveReduceSum(float v) {
    #pragma unroll
    for (int off = 32; off > 0; off >>= 1)
        v += __shfl_xor(v, off, 64);
    return v;
}
__device__ __forceinline__ float waveReduceMax(float v) {
    #pragma unroll
    for (int off = 32; off > 0; off >>= 1)
        v = fmaxf(v, __shfl_xor(v, off, 64));
    return v;
}

// Fixed, weakly-monotone log-spaced binning of u (exactness needs only
// monotonicity: within-bin membership resolved by explicit compare).
__device__ __forceinline__ int binOf(float x) {
    float a = fabsf(x);
    float f = log2f(fmaf(a, 1024.0f, 1.0f)) * 76.0f;
    int j = (int)f;
    j = min(j, 2047);
    return (x < 0.0f) ? (2047 - j) : (2048 + j);
}

// Device-scope grid barrier. Safe: GRID=80 blocks on 256 CUs are always
// co-resident. Monotone counter (target = phase * GRID) needs no reset
// between phases; zeroed per launch by the host-side memset.
__device__ __forceinline__ void gridBarrier(int* bar, int target) {
    __syncthreads();
    if (threadIdx.x == 0) {
        __hip_atomic_fetch_add(bar, 1, __ATOMIC_ACQ_REL, __HIP_MEMORY_SCOPE_AGENT);
        while (__hip_atomic_load(bar, __ATOMIC_ACQUIRE, __HIP_MEMORY_SCOPE_AGENT) < target)
            __builtin_amdgcn_s_sleep(1);
    }
    __syncthreads();
}

__global__ void __launch_bounds__(BLK)
ckd_mega_kernel(const float* __restrict__ ls,
                const float* __restrict__ lt,
                const int* __restrict__ target,
                float* __restrict__ t,
                float* __restrict__ s,
                float* __restrict__ u,
                float* __restrict__ acc,
                int* __restrict__ binCnt,
                float* __restrict__ binT,
                float* __restrict__ binS,
                int* __restrict__ binStart,
                float* __restrict__ cumT,
                float* __restrict__ cumS,
                int* __restrict__ cursor,
                float4* __restrict__ pack,
                float* __restrict__ out) {
    __shared__ int lc[SCAN_T];
    __shared__ float ltt[SCAN_T], lss[SCAN_T];
    __shared__ float red[4];
    int tid = threadIdx.x;
    int bx = blockIdx.x;
    int* bar = (int*)(acc + 12);

    // ================= Phase A: softmax + KD + cubes + u + histogram ========
    {
        int wave = bx * 4 + (tid >> 6);   // 0..319 = k*B + b
        int lane = tid & 63;
        int k = wave / B;
        int b = wave % B;
        float T = (float)(k + 1);
        float invT = 1.0f / T;

        const float* lsrow = ls + b * C;
        const float* ltrow = lt + b * C;

        int c0 = lane, c1 = lane + 64;
        bool h1 = (c1 < C);

        float as0 = lsrow[c0] * invT;
        float at0 = ltrow[c0] * invT;
        float as1 = h1 ? lsrow[c1] * invT : -INFINITY;
        float at1 = h1 ? ltrow[c1] * invT : -INFINITY;

        float ms = waveReduceMax(fmaxf(as0, as1));
        float mt = waveReduceMax(fmaxf(at0, at1));

        float es0 = expf(as0 - ms);
        float es1 = h1 ? expf(as1 - ms) : 0.0f;
        float et0 = expf(at0 - mt);
        float et1 = h1 ? expf(at1 - mt) : 0.0f;

        float Zs = waveReduceSum(es0 + es1);
        float Zt = waveReduceSum(et0 + et1);
        float logZs = logf(Zs), logZt = logf(Zt);
        float invZs = 1.0f / Zs, invZt = 1.0f / Zt;

        float q0 = es0 * invZs, q1 = es1 * invZs;   // student probs
        float p0 = et0 * invZt, p1 = et1 * invZt;   // teacher probs

        float lq0 = as0 - ms - logZs;
        float lp0 = at0 - mt - logZt;
        float lq1 = as1 - ms - logZs;
        float lp1 = at1 - mt - logZt;

        int rbase = (k * B + b) * C;
        float u0 = lq0 - lp0;
        t[rbase + c0] = p0;  s[rbase + c0] = q0;  u[rbase + c0] = u0;
        int j0 = binOf(u0);
        atomicAdd(&binCnt[j0], 1);
        atomicAdd(&binT[j0], p0);
        atomicAdd(&binS[j0], q0);
        if (h1) {
            float u1 = lq1 - lp1;
            t[rbase + c1] = p1; s[rbase + c1] = q1; u[rbase + c1] = u1;
            int j1 = binOf(u1);
            atomicAdd(&binCnt[j1], 1);
            atomicAdd(&binT[j1], p1);
            atomicAdd(&binS[j1], q1);
        }

        float kl_part = p0 * (lp0 - lq0) + (h1 ? p1 * (lp1 - lq1) : 0.0f);
        float klr = waveReduceSum(kl_part);
        float ttr = waveReduceSum(p0 * p0 + p1 * p1);
        float ssr = waveReduceSum(q0 * q0 + q1 * q1);
        float tsr = waveReduceSum(p0 * q0 + p1 * q1);

        float cer = 0.0f;
        if (k == 0) {
            int tg = target[b];
            float cl = (c0 == tg) ? lq0 : ((h1 && c1 == tg) ? lq1 : 0.0f);
            cer = waveReduceSum(cl);
        }

        if (lane == 0) {
            atomicAdd(&acc[0], klr * (ALPHA * T * T));
            atomicAdd(&acc[2], ttr);
            atomicAdd(&acc[3], ssr);
            atomicAdd(&acc[4], tsr);
            if (k == 0) atomicAdd(&acc[1], cer);
        }
    }
    gridBarrier(bar, GRID);

    // ============ Phase B: block 0 scans bins; blocks 1..79 do Grams ========
    if (bx == 0) {
        int r = tid;
        int base = r * PER_T;
        int cl_[PER_T]; float tl[PER_T], sl[PER_T];
        int cp = 0; float tp = 0.f, sp = 0.f;
        #pragma unroll
        for (int e = 0; e < PER_T; e++) {
            cp += binCnt[base + e]; cl_[e] = cp;
            tp += binT[base + e];   tl[e] = tp;
            sp += binS[base + e];   sl[e] = sp;
        }
        lc[r] = cp; ltt[r] = tp; lss[r] = sp;
        __syncthreads();
        for (int off = 1; off < SCAN_T; off <<= 1) {
            int cv = 0; float tv = 0.f, sv = 0.f;
            if (r >= off) { cv = lc[r - off]; tv = ltt[r - off]; sv = lss[r - off]; }
            __syncthreads();
            lc[r] += cv; ltt[r] += tv; lss[r] += sv;
            __syncthreads();
        }
        int   excC = lc[r]  - cp;
        float excT = ltt[r] - tp;
        float excS = lss[r] - sp;
        #pragma unroll
        for (int e = 0; e < PER_T; e++) {
            int bs = excC + (e ? cl_[e-1] : 0);
            binStart[base + e] = bs;
            cursor[base + e]   = bs;
            cumT[base + e] = excT + (e ? tl[e-1] : 0.f);
            cumS[base + e] = excS + (e ? sl[e-1] : 0.f);
        }
        if (r == SCAN_T - 1) {
            binStart[M] = lc[r];
            cumT[M] = ltt[r];
            cumS[M] = lss[r];
        }
    } else {
        const int NG = K * B * B;   // 20480
        const int NH = K * C * C;   // 50000
        float g2 = 0.0f, h2 = 0.0f;
        for (int item = (bx - 1) * BLK + tid; item < NG + NH; item += (GRID - 1) * BLK) {
            if (item < NG) {
                int k = item / (B * B);
                int r = item % (B * B);
                int i = r >> 6, j = r & 63;
                const float* Ti = t + (k * B + i) * C;
                const float* Si = s + (k * B + i) * C;
                const float* Tj = t + (k * B + j) * C;
                const float* Sj = s + (k * B + j) * C;
                float gt = 0.0f, gs = 0.0f;
                #pragma unroll 4
                for (int c = 0; c < C; c++) {
                    gt = fmaf(Ti[c], Tj[c], gt);
                    gs = fmaf(Si[c], Sj[c], gs);
                }
                float g = gt - gs;
                g2 += g * g;
            } else {
                int it2 = item - NG;
                int k = it2 / (C * C);
                int r = it2 % (C * C);
                int i = r / C, j = r % C;
                const float* Tk = t + k * B * C;
                const float* Sk = s + k * B * C;
                float ht = 0.0f, hs = 0.0f;
                #pragma unroll 4
                for (int b = 0; b < B; b++) {
                    ht = fmaf(Tk[b * C + i], Tk[b * C + j], ht);
                    hs = fmaf(Sk[b * C + i], Sk[b * C + j], hs);
                }
                float h = ht - hs;
                h2 += h * h;
            }
        }
        float gr = waveReduceSum(g2);
        float hr = waveReduceSum(h2);
        if ((tid & 63) == 0) {
            atomicAdd(&acc[5], gr);
            atomicAdd(&acc[6], hr);
        }
    }
    gridBarrier(bar, 2 * GRID);

    // ================= Phase C: scatter into bin-sorted pack ================
    for (int i = bx * BLK + tid; i < N; i += GRID * BLK) {
        float x = u[i];
        int j = binOf(x);
        int pos = atomicAdd(&cursor[j], 1);
        pack[pos] = make_float4(x, t[i], s[i], 0.f);
    }
    gridBarrier(bar, 3 * GRID);

    // ================= Phase D: L1 closed form per a ========================
    {
        float T_tot = cumT[M], S_tot = cumS[M];
        float rowsum = 0.0f;
        for (int a = bx * BLK + tid; a < N; a += GRID * BLK) {
            float x = -u[a];
            int j = binOf(x);
            float T_le = cumT[j], S_le = cumS[j];
            int p0 = binStart[j], p1 = binStart[j + 1];
            for (int p = p0; p < p1; p++) {
                float4 v = pack[p];
                if (v.x <= x) { T_le += v.y; S_le += v.z; }
            }
            rowsum += t[a] * (2.0f * T_le - T_tot) + s[a] * (S_tot - 2.0f * S_le);
        }
        float r = waveReduceSum(rowsum);
        int wid = tid >> 6;
        if ((tid & 63) == 0) red[wid] = r;
        __syncthreads();
        if (tid == 0) atomicAdd(&acc[7], (red[0] + red[1]) + (red[2] + red[3]));
    }
    gridBarrier(bar, 4 * GRID);

    // ================= Phase E: finalize ====================================
    if (bx == 0 && tid == 0) {
        float kl = acc[0] / (float)(B * C);
        float ce = -acc[1] / (float)B;
        float kd = kl + (float)(K) * (1.0f - ALPHA) * ce;
        float tt = acc[2], ss = acc[3], ts = acc[4];
        float l2 = L1L2_SCALE * (tt * tt - 2.0f * ts * ts + ss * ss);
        float l1 = L1L2_SCALE * acc[7];
        float sub = acc[5] + acc[6];
        out[0] = kd + l1 + l2 + sub;
    }
}

extern "C" void kernel_launch(void* const* d_in, const int* in_sizes, int n_in,
                              void* d_out, int out_size, void* d_ws, size_t ws_size,
                              hipStream_t stream) {
    const float* ls = (const float*)d_in[0];
    const float* lt = (const float*)d_in[1];
    const int* tg = (const int*)d_in[2];

    // workspace layout (pack is 16B-aligned: 3N*4 = 384000 % 16 == 0)
    float* t = (float*)d_ws;            // N
    float* s = t + N;                   // N
    float* u = s + N;                   // N
    float4* pack = (float4*)(u + N);    // N float4
    float* acc = (float*)(pack + N);    // 16 (incl. barrier counter at [12])
    int* binCnt = (int*)(acc + 16);     // M
    float* binT = (float*)(binCnt + M); // M
    float* binS = binT + M;             // M
    int* binStart = (int*)(binS + M);   // M+1
    float* cumT = (float*)(binStart + (M + 1)); // M+1
    float* cumS = cumT + (M + 1);       // M+1
    int* cursor = (int*)(cumS + (M + 1)); // M

    // zero acc (incl. barrier) + binCnt + binT + binS
    hipMemsetAsync(acc, 0, (16 + 3 * M) * sizeof(float), stream);

    ckd_mega_kernel<<<GRID, BLK, 0, stream>>>(ls, lt, tg, t, s, u, acc,
                                              binCnt, binT, binS,
                                              binStart, cumT, cumS, cursor,
                                              pack, (float*)d_out);
}

// Round 6
// 97.963 us; speedup vs baseline: 1.8979x; 1.8979x over previous
//
#include <hip/hip_runtime.h>
#include <math.h>

#define B 64
#define C 100
#define K 5
#define N (B*C*K)   // 32000
#define M 4096      // L1 bucket count (log-spaced over u)

#define ALPHA 0.7f
#define L1L2_SCALE 0.00025f

#define SCAN_T 256
#define PER_T (M / SCAN_T)   // 16

// acc layout (floats):
// 0: KL acc  1: CE acc  2: tt  3: ss  4: ts  5: sum G^2  6: sum H^2

__device__ __forceinline__ float waveReduceSum(float v) {
    #pragma unroll
    for (int off = 32; off > 0; off >>= 1)
        v += __shfl_xor(v, off, 64);
    return v;
}
__device__ __forceinline__ float waveReduceMax(float v) {
    #pragma unroll
    for (int off = 32; off > 0; off >>= 1)
        v = fmaxf(v, __shfl_xor(v, off, 64));
    return v;
}

// Fixed, weakly-monotone log-spaced binning of u = log(s)-log(t).
// Bin-granular L1 is exact up to pairs with |u_a+u_b| < binwidth, whose
// contribution |t_a t_b - s_a s_b| <= t_a t_b * binwidth ~ 0 by construction.
// binOf(-x) == 4095 - binOf(x)  (mirror symmetry used by the dot product).
__device__ __forceinline__ int binOf(float x) {
    float a = fabsf(x);
    float f = log2f(fmaf(a, 1024.0f, 1.0f)) * 76.0f;
    int j = (int)f;
    j = min(j, 2047);
    return (x < 0.0f) ? (2047 - j) : (2048 + j);
}

// One wave per (k, b) row: softmaxes at temp k+1, write cubes t,s,
// accumulate KL, CE (k==0), tt/ss/ts, and histogram (t, s) per u-bin.
__global__ void softmax_kd_hist_kernel(const float* __restrict__ ls,
                                       const float* __restrict__ lt,
                                       const int* __restrict__ target,
                                       float* __restrict__ t,
                                       float* __restrict__ s,
                                       float* __restrict__ acc,
                                       float* __restrict__ binT,
                                       float* __restrict__ binS) {
    int blk = blockIdx.x;       // 0..K*B-1
    int k = blk / B;
    int b = blk % B;
    int tid = threadIdx.x;      // 0..63
    float T = (float)(k + 1);
    float invT = 1.0f / T;

    const float* lsrow = ls + b * C;
    const float* ltrow = lt + b * C;

    int c0 = tid, c1 = tid + 64;
    bool h1 = (c1 < C);

    float as0 = lsrow[c0] * invT;
    float at0 = ltrow[c0] * invT;
    float as1 = h1 ? lsrow[c1] * invT : -INFINITY;
    float at1 = h1 ? ltrow[c1] * invT : -INFINITY;

    float ms = waveReduceMax(fmaxf(as0, as1));
    float mt = waveReduceMax(fmaxf(at0, at1));

    float es0 = expf(as0 - ms);
    float es1 = h1 ? expf(as1 - ms) : 0.0f;
    float et0 = expf(at0 - mt);
    float et1 = h1 ? expf(at1 - mt) : 0.0f;

    float Zs = waveReduceSum(es0 + es1);
    float Zt = waveReduceSum(et0 + et1);
    float logZs = logf(Zs), logZt = logf(Zt);
    float invZs = 1.0f / Zs, invZt = 1.0f / Zt;

    float q0 = es0 * invZs, q1 = es1 * invZs;   // student probs
    float p0 = et0 * invZt, p1 = et1 * invZt;   // teacher probs

    float lq0 = as0 - ms - logZs;
    float lp0 = at0 - mt - logZt;
    float lq1 = as1 - ms - logZs;
    float lp1 = at1 - mt - logZt;

    int rbase = (k * B + b) * C;
    float u0 = lq0 - lp0;
    t[rbase + c0] = p0;  s[rbase + c0] = q0;
    int j0 = binOf(u0);
    atomicAdd(&binT[j0], p0);
    atomicAdd(&binS[j0], q0);
    if (h1) {
        float u1 = lq1 - lp1;
        t[rbase + c1] = p1; s[rbase + c1] = q1;
        int j1 = binOf(u1);
        atomicAdd(&binT[j1], p1);
        atomicAdd(&binS[j1], q1);
    }

    float kl_part = p0 * (lp0 - lq0) + (h1 ? p1 * (lp1 - lq1) : 0.0f);
    float klr = waveReduceSum(kl_part);
    float ttr = waveReduceSum(p0 * p0 + p1 * p1);
    float ssr = waveReduceSum(q0 * q0 + q1 * q1);
    float tsr = waveReduceSum(p0 * q0 + p1 * q1);

    float cer = 0.0f;
    if (k == 0) {
        int tg = target[b];
        float cl = (c0 == tg) ? lq0 : ((h1 && c1 == tg) ? lq1 : 0.0f);
        cer = waveReduceSum(cl);
    }

    if (tid == 0) {
        atomicAdd(&acc[0], klr * (ALPHA * T * T));
        atomicAdd(&acc[2], ttr);
        atomicAdd(&acc[3], ssr);
        atomicAdd(&acc[4], tsr);
        if (k == 0) atomicAdd(&acc[1], cer);
    }
}

// Fused Gram losses, one dispatch, 128 threads/block (round-4 proven).
// Blocks [0,160): G over (k,i) pairs, lanes = j. Blocks [160,660): H.
__global__ void gram_kernel(const float* __restrict__ t,
                            const float* __restrict__ s,
                            float* __restrict__ acc) {
    int bx = blockIdx.x;
    int tid = threadIdx.x;
    if (bx < 160) {
        int wave = tid >> 6, lane = tid & 63;
        int k = bx / 32;
        int i = (bx % 32) * 2 + wave;
        int j = lane;
        const float* Ti = t + (k * B + i) * C;
        const float* Si = s + (k * B + i) * C;
        const float* Tj = t + (k * B + j) * C;
        const float* Sj = s + (k * B + j) * C;
        float gt = 0.0f, gs = 0.0f;
        #pragma unroll 4
        for (int c = 0; c < C; c++) {
            gt = fmaf(Ti[c], Tj[c], gt);
            gs = fmaf(Si[c], Sj[c], gs);
        }
        float g = gt - gs;
        float r = waveReduceSum(g * g);
        if (lane == 0) atomicAdd(&acc[5], r);
    } else {
        int b2 = bx - 160;          // k*C + i
        int k = b2 / C, i = b2 % C;
        int j = tid;                // 0..127
        __shared__ float red[2];
        float h2 = 0.0f;
        if (j < C) {
            const float* Tk = t + k * B * C;
            const float* Sk = s + k * B * C;
            float ht = 0.0f, hs = 0.0f;
            #pragma unroll 4
            for (int b = 0; b < B; b++) {
                ht = fmaf(Tk[b * C + i], Tk[b * C + j], ht);
                hs = fmaf(Sk[b * C + i], Sk[b * C + j], hs);
            }
            float h = ht - hs;
            h2 = h * h;
        }
        float r = waveReduceSum(h2);
        int wid = j >> 6;
        if ((j & 63) == 0) red[wid] = r;
        __syncthreads();
        if (tid == 0) atomicAdd(&acc[6], red[0] + red[1]);
    }
}

// Single block: exclusive scan of binT/binS into LDS, mirrored dot product,
// then finalize the whole loss (acc[0..6] from the two prior dispatches).
__global__ void __launch_bounds__(SCAN_T)
scan_dot_finalize_kernel(const float* __restrict__ binT,
                         const float* __restrict__ binS,
                         const float* __restrict__ acc,
                         float* __restrict__ out) {
    __shared__ float cT[M], cS[M];     // exclusive prefix sums
    __shared__ float ltt[SCAN_T], lss[SCAN_T];
    __shared__ float redT[4], redS[4];
    __shared__ float totTS[2];
    int r = threadIdx.x;
    int base = r * PER_T;

    float tl[PER_T], sl[PER_T];
    float tp = 0.f, sp = 0.f;
    #pragma unroll
    for (int e = 0; e < PER_T; e++) {
        tp += binT[base + e]; tl[e] = tp;
        sp += binS[base + e]; sl[e] = sp;
    }
    ltt[r] = tp; lss[r] = sp;
    __syncthreads();
    for (int off = 1; off < SCAN_T; off <<= 1) {
        float tv = 0.f, sv = 0.f;
        if (r >= off) { tv = ltt[r - off]; sv = lss[r - off]; }
        __syncthreads();
        ltt[r] += tv; lss[r] += sv;
        __syncthreads();
    }
    float excT = ltt[r] - tp;
    float excS = lss[r] - sp;
    #pragma unroll
    for (int e = 0; e < PER_T; e++) {
        cT[base + e] = excT + (e ? tl[e-1] : 0.f);
        cS[base + e] = excS + (e ? sl[e-1] : 0.f);
    }
    if (r == SCAN_T - 1) { totTS[0] = ltt[r]; totTS[1] = lss[r]; }
    __syncthreads();

    // dot: sum_m binT[m]*cT[4095-m], sum_m binS[m]*cS[4095-m]
    float dT = 0.f, dS = 0.f;
    #pragma unroll
    for (int e = 0; e < PER_T; e++) {
        int m = base + e;
        float bt = tl[e] - (e ? tl[e-1] : 0.f);   // = binT[m] (from registers)
        float bs = sl[e] - (e ? sl[e-1] : 0.f);
        dT = fmaf(bt, cT[4095 - m], dT);
        dS = fmaf(bs, cS[4095 - m], dS);
    }
    float rT = waveReduceSum(dT);
    float rS = waveReduceSum(dS);
    int wid = r >> 6;
    if ((r & 63) == 0) { redT[wid] = rT; redS[wid] = rS; }
    __syncthreads();

    if (r == 0) {
        float dotT = (redT[0] + redT[1]) + (redT[2] + redT[3]);
        float dotS = (redS[0] + redS[1]) + (redS[2] + redS[3]);
        float T_tot = totTS[0], S_tot = totTS[1];
        float l1sum = 2.0f * dotT - T_tot * T_tot + S_tot * S_tot - 2.0f * dotS;

        float kl = acc[0] / (float)(B * C);
        float ce = -acc[1] / (float)B;
        float kd = kl + (float)(K) * (1.0f - ALPHA) * ce;
        float tt = acc[2], ss = acc[3], ts = acc[4];
        float l2 = L1L2_SCALE * (tt * tt - 2.0f * ts * ts + ss * ss);
        float l1 = L1L2_SCALE * l1sum;
        float sub = acc[5] + acc[6];
        out[0] = kd + l1 + l2 + sub;
    }
}

extern "C" void kernel_launch(void* const* d_in, const int* in_sizes, int n_in,
                              void* d_out, int out_size, void* d_ws, size_t ws_size,
                              hipStream_t stream) {
    const float* ls = (const float*)d_in[0];
    const float* lt = (const float*)d_in[1];
    const int* tg = (const int*)d_in[2];

    float* t = (float*)d_ws;       // N
    float* s = t + N;              // N
    float* acc = s + N;            // 16
    float* binT = acc + 16;        // M
    float* binS = binT + M;        // M

    // zero acc + binT + binS (33 KB)
    hipMemsetAsync(acc, 0, (16 + 2 * M) * sizeof(float), stream);

    softmax_kd_hist_kernel<<<K * B, 64, 0, stream>>>(ls, lt, tg, t, s, acc, binT, binS);
    gram_kernel<<<660, 128, 0, stream>>>(t, s, acc);
    scan_dot_finalize_kernel<<<1, SCAN_T, 0, stream>>>(binT, binS, acc, (float*)d_out);
}